// Round 5
// baseline (413.163 us; speedup 1.0000x reference)
//
#include <hip/hip_runtime.h>
#include <hip/hip_bf16.h>

// Problem constants
#define B_     16384
#define TD     512     // T*D
#define HID    128
#define LAT    512     // N_TOKENS*CODE_DIM
#define NCODES 512
#define CDIM   64
#define EPS    1e-5f
#define DELTA  2.0f    // rescore margin: >> 2*eps_bf16 (~0.64) for this data

typedef __attribute__((ext_vector_type(8))) short bf16x8;
typedef __attribute__((ext_vector_type(4))) float f32x4;

// fp32 -> bf16 round-to-nearest-even (bit trick; no NaN inputs here)
static __device__ __forceinline__ unsigned short f2bf(float x) {
    unsigned int u = __float_as_uint(x);
    u = (u + 0x7FFFu + ((u >> 16) & 1u)) >> 16;
    return (unsigned short)u;
}

// ---------------------------------------------------------------------------
// c2[c] = sum_d codebook[c][d]^2   (one wave per code)
// ---------------------------------------------------------------------------
__global__ void c2_kernel(const float* __restrict__ cb, float* __restrict__ c2) {
    int c = blockIdx.x;
    int d = threadIdx.x;            // 64 threads = 1 wave
    float v = cb[c * CDIM + d];
    float s = v * v;
#pragma unroll
    for (int m = 32; m >= 1; m >>= 1) s += __shfl_xor(s, m, 64);
    if (d == 0) c2[c] = s;
}

// ---------------------------------------------------------------------------
// Weight/codebook prep: w1t[n=128][k=512] = bf16(dec_w1[k][n]),
// w2t[n=512][k=128] = bf16(dec_w2[k][n]), cbfrag = codebook in MFMA
// B-fragment order: slot ((nt*2+kk)*64 + q*16 + l15)*8 + j holds
// cb[code=nt*16+l15][dim=kk*32+q*8+j].   163840 threads total.
// ---------------------------------------------------------------------------
__global__ void prep_kernel(const float* __restrict__ w1, const float* __restrict__ w2,
                            const float* __restrict__ cb,
                            unsigned short* __restrict__ w1t, unsigned short* __restrict__ w2t,
                            unsigned short* __restrict__ cbfrag) {
    int i = blockIdx.x * 256 + threadIdx.x;      // 0..163839
    if (i < 65536) {
        int n = i >> 9, k = i & 511;             // w1t[n][k]
        w1t[i] = f2bf(w1[k * HID + n]);
    } else if (i < 131072) {
        int j = i - 65536;
        int n = j >> 7, k = j & 127;             // w2t[n][k]
        w2t[j] = f2bf(w2[k * TD + n]);
    } else {
        int e    = i - 131072;                   // 0..32767
        int code = e >> 6, dim = e & 63;
        int nt = code >> 4, l15 = code & 15;
        int kk = dim >> 5, q = (dim & 31) >> 3, j = dim & 7;
        cbfrag[((nt * 2 + kk) * 64 + q * 16 + l15) * 8 + j] = f2bf(cb[code * CDIM + dim]);
    }
}

// ---------------------------------------------------------------------------
// fp32 GEMM (encoder) — UNCHANGED from round 4 (bit-identical z path).
// ---------------------------------------------------------------------------
template<bool RELU, bool LN>
__launch_bounds__(256)
__global__ void gemm_f32(const float* __restrict__ A, const float* __restrict__ W,
                         const float* __restrict__ bias, float* __restrict__ C,
                         int N, int K) {
    __shared__ float As[32 * 132];   // As[k*132 + m], m=0..127
    __shared__ float Ws[32 * 68];    // Ws[k*68 + n],  n=0..63

    const int tid = threadIdx.x;
    const int tx  = tid & 15;
    const int ty  = tid >> 4;
    const int n0  = blockIdx.x * 64;
    const int m0  = blockIdx.y * 128;

    float acc[8][4] = {};

    for (int k0 = 0; k0 < K; k0 += 32) {
        if (k0) __syncthreads();
#pragma unroll
        for (int p = 0; p < 4; ++p) {
            int idx = p * 256 + tid;
            int r   = idx >> 3;
            int k4  = (idx & 7) * 4;
            float4 v = *(const float4*)&A[(size_t)(m0 + r) * K + k0 + k4];
            As[(k4 + 0) * 132 + r] = v.x;
            As[(k4 + 1) * 132 + r] = v.y;
            As[(k4 + 2) * 132 + r] = v.z;
            As[(k4 + 3) * 132 + r] = v.w;
        }
#pragma unroll
        for (int p = 0; p < 2; ++p) {
            int idx = p * 256 + tid;
            int k   = idx >> 4;
            int c4  = (idx & 15) * 4;
            *(float4*)&Ws[k * 68 + c4] = *(const float4*)&W[(size_t)(k0 + k) * N + n0 + c4];
        }
        __syncthreads();

#pragma unroll 8
        for (int k = 0; k < 32; ++k) {
            float a0[8], w0[4];
            *(float4*)&a0[0] = *(const float4*)&As[k * 132 + ty * 8];
            *(float4*)&a0[4] = *(const float4*)&As[k * 132 + ty * 8 + 4];
            *(float4*)&w0[0] = *(const float4*)&Ws[k * 68 + tx * 4];
#pragma unroll
            for (int i = 0; i < 8; ++i)
#pragma unroll
                for (int j = 0; j < 4; ++j)
                    acc[i][j] = fmaf(a0[i], w0[j], acc[i][j]);
        }
    }

    float bv[4];
#pragma unroll
    for (int j = 0; j < 4; ++j) bv[j] = bias[n0 + tx * 4 + j];

#pragma unroll
    for (int i = 0; i < 8; ++i) {
        float c[4];
#pragma unroll
        for (int j = 0; j < 4; ++j) {
            c[j] = acc[i][j] + bv[j];
            if (RELU) c[j] = fmaxf(c[j], 0.0f);
        }
        if (LN) {
            float s  = c[0] + c[1] + c[2] + c[3];
            float ss = c[0]*c[0] + c[1]*c[1] + c[2]*c[2] + c[3]*c[3];
#pragma unroll
            for (int m = 1; m <= 8; m <<= 1) {
                s  += __shfl_xor(s,  m, 64);
                ss += __shfl_xor(ss, m, 64);
            }
            float mean = s * (1.0f / 64.0f);
            float var  = ss * (1.0f / 64.0f) - mean * mean;
            float rstd = rsqrtf(var + EPS);
#pragma unroll
            for (int j = 0; j < 4; ++j) c[j] = (c[j] - mean) * rstd;
        }
        *(float4*)&C[(size_t)(m0 + ty * 8 + i) * N + n0 + tx * 4] =
            make_float4(c[0], c[1], c[2], c[3]);
    }
}

// ---------------------------------------------------------------------------
// VQ via MFMA prefilter + exact fp32 rescore. 128 tokens/block, 1024 blocks.
// Pass 1: bf16 MFMA approx scores (c2 - 2*dot_bf16) -> per-token approx min.
// Pass 2: re-MFMA; entries with approx < min+DELTA get exact fp32 rescore,
//         committed via order-preserving packed u64 atomicMin (tie -> lower
//         code index == numpy first-min semantics).
// Guarantee: approx(c*) <= exact_min + eps <= minA + 2*eps < minA + DELTA.
// ---------------------------------------------------------------------------
__launch_bounds__(256)
__global__ void vq_mfma(const float* __restrict__ zln, const float* __restrict__ cb,
                        const unsigned short* __restrict__ cbfrag,
                        const float* __restrict__ c2, float* __restrict__ zq_ws,
                        float* __restrict__ zq_out, float* __restrict__ idx_out) {
    __shared__ float Zs32[128 * 64];                 // 32 KB fp32 z (rescore)
    __shared__ unsigned short Zb[8 * 2 * 64 * 8];    // 16 KB bf16 A-fragments
    __shared__ float c2s[NCODES];                    // 2 KB
    __shared__ float minA[128];
    __shared__ unsigned long long packed[128];       // (key<<32)|code

    const int tid = threadIdx.x;
    const int m0  = blockIdx.x * 128;

    // ---- stage z: fp32 copy + bf16 A-fragment layout ----
#pragma unroll
    for (int p = 0; p < 8; ++p) {
        int idx = p * 256 + tid;              // 0..2047
        int tok = idx >> 4;                   // 0..127
        int d4  = (idx & 15) * 4;             // 0..60
        float4 v = *(const float4*)&zln[(size_t)(m0 + tok) * CDIM + d4];
        *(float4*)&Zs32[tok * 64 + d4] = v;
        int mt = tok >> 4, l15 = tok & 15, kk = d4 >> 5, q = (d4 & 31) >> 3, j = d4 & 7;
        ushort4 b;
        b.x = f2bf(v.x); b.y = f2bf(v.y); b.z = f2bf(v.z); b.w = f2bf(v.w);
        *(ushort4*)&Zb[((mt * 2 + kk) * 64 + q * 16 + l15) * 8 + j] = b;
    }
    c2s[tid]       = c2[tid];
    c2s[tid + 256] = c2[tid + 256];
    if (tid < 128) packed[tid] = ~0ULL;
    __syncthreads();

    const int w = tid >> 6, ln = tid & 63, l15 = ln & 15, q = ln >> 4;
    const bf16x8* cbf = (const bf16x8*)cbfrag;

    // A-fragments for this wave's two m-tiles (held in regs for both passes)
    bf16x8 a[2][2];
#pragma unroll
    for (int mi = 0; mi < 2; ++mi)
#pragma unroll
        for (int kk = 0; kk < 2; ++kk)
            a[mi][kk] = *(const bf16x8*)&Zb[(((2 * w + mi) * 2 + kk) * 64 + ln) * 8];

    // ---- pass 1: approx min per token ----
    float mn[2][4];
#pragma unroll
    for (int mi = 0; mi < 2; ++mi)
#pragma unroll
        for (int r = 0; r < 4; ++r) mn[mi][r] = 3.4e38f;

    for (int nt = 0; nt < 32; ++nt) {
        bf16x8 b0 = cbf[(nt * 2 + 0) * 64 + ln];
        bf16x8 b1 = cbf[(nt * 2 + 1) * 64 + ln];
        float c2v = c2s[nt * 16 + l15];
#pragma unroll
        for (int mi = 0; mi < 2; ++mi) {
            f32x4 acc = {0.f, 0.f, 0.f, 0.f};
            acc = __builtin_amdgcn_mfma_f32_16x16x32_bf16(a[mi][0], b0, acc, 0, 0, 0);
            acc = __builtin_amdgcn_mfma_f32_16x16x32_bf16(a[mi][1], b1, acc, 0, 0, 0);
#pragma unroll
            for (int r = 0; r < 4; ++r) {
                float s = fmaf(-2.0f, acc[r], c2v);
                mn[mi][r] = fminf(mn[mi][r], s);
            }
        }
    }
#pragma unroll
    for (int mi = 0; mi < 2; ++mi)
#pragma unroll
        for (int r = 0; r < 4; ++r) {
            float v = mn[mi][r];
#pragma unroll
            for (int m = 1; m <= 8; m <<= 1) v = fminf(v, __shfl_xor(v, m, 64));
            if (l15 == 0) minA[(2 * w + mi) * 16 + q * 4 + r] = v;
        }
    __syncthreads();

    float thr[2][4];
#pragma unroll
    for (int mi = 0; mi < 2; ++mi)
#pragma unroll
        for (int r = 0; r < 4; ++r)
            thr[mi][r] = minA[(2 * w + mi) * 16 + q * 4 + r] + DELTA;

    // ---- pass 2: re-MFMA + exact fp32 rescore of candidates ----
    for (int nt = 0; nt < 32; ++nt) {
        bf16x8 b0 = cbf[(nt * 2 + 0) * 64 + ln];
        bf16x8 b1 = cbf[(nt * 2 + 1) * 64 + ln];
        float c2v = c2s[nt * 16 + l15];
#pragma unroll
        for (int mi = 0; mi < 2; ++mi) {
            f32x4 acc = {0.f, 0.f, 0.f, 0.f};
            acc = __builtin_amdgcn_mfma_f32_16x16x32_bf16(a[mi][0], b0, acc, 0, 0, 0);
            acc = __builtin_amdgcn_mfma_f32_16x16x32_bf16(a[mi][1], b1, acc, 0, 0, 0);
#pragma unroll
            for (int r = 0; r < 4; ++r) {
                float s = fmaf(-2.0f, acc[r], c2v);
                if (s < thr[mi][r]) {
                    int t    = (2 * w + mi) * 16 + q * 4 + r;   // block-local token
                    int code = nt * 16 + l15;
                    const float* zp = &Zs32[t * 64];
                    const float* cp = &cb[(size_t)code * CDIM];
                    float a0 = 0.f, a1 = 0.f, a2 = 0.f, a3 = 0.f;
#pragma unroll
                    for (int k = 0; k < 64; k += 4) {
                        a0 = fmaf(zp[k + 0], cp[k + 0], a0);
                        a1 = fmaf(zp[k + 1], cp[k + 1], a1);
                        a2 = fmaf(zp[k + 2], cp[k + 2], a2);
                        a3 = fmaf(zp[k + 3], cp[k + 3], a3);
                    }
                    float dot = (a0 + a1) + (a2 + a3);
                    float es  = fmaf(-2.0f, dot, c2s[code]);
                    unsigned int u = __float_as_uint(es);
                    u ^= ((unsigned int)((int)u >> 31)) | 0x80000000u;
                    unsigned long long key =
                        ((unsigned long long)u << 32) | (unsigned int)code;
                    atomicMin(&packed[t], key);
                }
            }
        }
    }
    __syncthreads();

    // ---- output: 16 lanes per token, coalesced 256B rows ----
    const int tx = tid & 15, ty = tid >> 4;
#pragma unroll
    for (int it = 0; it < 8; ++it) {
        int tok = it * 16 + ty;
        int bi  = (int)(packed[tok] & 0xFFFFFFFFULL);
        int row = m0 + tok;
        float4 qv = *(const float4*)&cb[(size_t)bi * CDIM + tx * 4];
        *(float4*)&zq_ws [(size_t)row * CDIM + tx * 4] = qv;
        *(float4*)&zq_out[(size_t)row * CDIM + tx * 4] = qv;
        if (tx == 0) idx_out[row] = (float)bi;
    }
}

// ---------------------------------------------------------------------------
// Decoder GEMM1 (MFMA bf16) — unchanged from round 4.
// ---------------------------------------------------------------------------
__launch_bounds__(256)
__global__ void dec1_mfma(const float* __restrict__ zq, const unsigned short* __restrict__ w1t,
                          const float* __restrict__ b1, unsigned short* __restrict__ h2) {
    const int tid = threadIdx.x;
    const int wv  = tid >> 6;
    const int ln  = tid & 63;
    const int l15 = ln & 15, q = ln >> 4;
    const int mt  = blockIdx.x * 2 + (wv >> 1);
    const int nh  = wv & 1;
    const int m   = mt * 16 + l15;

    f32x4 acc[4] = {};

    for (int k0 = 0; k0 < 512; k0 += 32) {
        const float* ap = &zq[(size_t)m * 512 + k0 + q * 8];
        float4 a1 = *(const float4*)ap;
        float4 a2 = *(const float4*)(ap + 4);
        bf16x8 a;
        a[0] = (short)f2bf(a1.x); a[1] = (short)f2bf(a1.y);
        a[2] = (short)f2bf(a1.z); a[3] = (short)f2bf(a1.w);
        a[4] = (short)f2bf(a2.x); a[5] = (short)f2bf(a2.y);
        a[6] = (short)f2bf(a2.z); a[7] = (short)f2bf(a2.w);
#pragma unroll
        for (int t = 0; t < 4; ++t) {
            int n = (nh * 4 + t) * 16 + l15;
            bf16x8 b = *(const bf16x8*)&w1t[(size_t)n * 512 + k0 + q * 8];
            acc[t] = __builtin_amdgcn_mfma_f32_16x16x32_bf16(a, b, acc[t], 0, 0, 0);
        }
    }
#pragma unroll
    for (int t = 0; t < 4; ++t) {
        int col = (nh * 4 + t) * 16 + l15;
        float bb = b1[col];
#pragma unroll
        for (int r = 0; r < 4; ++r) {
            int row = mt * 16 + q * 4 + r;
            float v = fmaxf(acc[t][r] + bb, 0.0f);
            h2[(size_t)row * 128 + col] = f2bf(v);
        }
    }
}

// ---------------------------------------------------------------------------
// Decoder GEMM2 (MFMA bf16) — unchanged from round 4.
// ---------------------------------------------------------------------------
__launch_bounds__(256)
__global__ void dec2_mfma(const unsigned short* __restrict__ h2, const unsigned short* __restrict__ w2t,
                          const float* __restrict__ b2, float* __restrict__ recon) {
    const int tid = threadIdx.x;
    const int wv  = tid >> 6, ln = tid & 63;
    const int l15 = ln & 15, q = ln >> 4;
    const int mt  = blockIdx.x;
    const int m   = mt * 16 + l15;

    f32x4 acc[8] = {};
#pragma unroll
    for (int k0 = 0; k0 < 128; k0 += 32) {
        bf16x8 a = *(const bf16x8*)&h2[(size_t)m * 128 + k0 + q * 8];
#pragma unroll
        for (int t = 0; t < 8; ++t) {
            int n = (wv * 8 + t) * 16 + l15;
            bf16x8 b = *(const bf16x8*)&w2t[(size_t)n * 128 + k0 + q * 8];
            acc[t] = __builtin_amdgcn_mfma_f32_16x16x32_bf16(a, b, acc[t], 0, 0, 0);
        }
    }
#pragma unroll
    for (int t = 0; t < 8; ++t) {
        int col = (wv * 8 + t) * 16 + l15;
        float bb = b2[col];
#pragma unroll
        for (int r = 0; r < 4; ++r) {
            int row = mt * 16 + q * 4 + r;
            recon[(size_t)row * 512 + col] = acc[t][r] + bb;
        }
    }
}

// ---------------------------------------------------------------------------
extern "C" void kernel_launch(void* const* d_in, const int* in_sizes, int n_in,
                              void* d_out, int out_size, void* d_ws, size_t ws_size,
                              hipStream_t stream) {
    const float* x      = (const float*)d_in[0];
    const float* enc_w1 = (const float*)d_in[1];
    const float* enc_b1 = (const float*)d_in[2];
    const float* enc_w2 = (const float*)d_in[3];
    const float* enc_b2 = (const float*)d_in[4];
    const float* cbk    = (const float*)d_in[5];
    const float* dec_w1 = (const float*)d_in[6];
    const float* dec_b1 = (const float*)d_in[7];
    const float* dec_w2 = (const float*)d_in[8];
    const float* dec_b2 = (const float*)d_in[9];

    // outputs, all float32, concatenated flat: recon | z_q | indices
    float* out     = (float*)d_out;
    float* recon_o = out;
    float* zq_o    = out + (size_t)B_ * TD;
    float* idx_o   = out + 2 * (size_t)B_ * TD;

    // workspace:
    //   zbuf [B,512] f32 (z_e_ln then z_q) | hbuf [B,128] f32 | c2 [512] f32
    //   hbuf reuse after enc2: [0,4MB) h2 bf16; +6MB: w1t(128K) w2t(128K) cbfrag(64K)
    float* zbuf  = (float*)d_ws;
    float* hbuf  = zbuf + (size_t)B_ * TD;
    float* c2buf = hbuf + (size_t)B_ * HID;
    unsigned short* h2bf   = (unsigned short*)hbuf;
    unsigned short* w1t    = (unsigned short*)(hbuf + 1572864);
    unsigned short* w2t    = w1t + 65536;
    unsigned short* cbfrag = w2t + 65536;

    hipLaunchKernelGGL(c2_kernel, dim3(NCODES), dim3(64), 0, stream, cbk, c2buf);

    // encoder GEMM1 + ReLU: [B,512]@[512,128] -> hbuf   grid (2,128)
    hipLaunchKernelGGL((gemm_f32<true, false>), dim3(HID / 64, B_ / 128), dim3(256), 0,
                       stream, x, enc_w1, enc_b1, hbuf, HID, TD);

    // encoder GEMM2 + LN: [B,128]@[128,512] -> zbuf     grid (8,128)
    hipLaunchKernelGGL((gemm_f32<false, true>), dim3(LAT / 64, B_ / 128), dim3(256), 0,
                       stream, hbuf, enc_w2, enc_b2, zbuf, LAT, HID);

    // weight + codebook-fragment prep (after enc2 has consumed hbuf)
    hipLaunchKernelGGL(prep_kernel, dim3(640), dim3(256), 0, stream,
                       dec_w1, dec_w2, cbk, w1t, w2t, cbfrag);

    // VQ: MFMA prefilter + exact rescore; 1024 blocks x 128 tokens
    hipLaunchKernelGGL(vq_mfma, dim3(B_ * 8 / 128), dim3(256), 0, stream,
                       zbuf, cbk, cbfrag, c2buf, zbuf, zq_o, idx_o);

    // decoder GEMM1 (MFMA): z_q -> h2 bf16              grid 512
    hipLaunchKernelGGL(dec1_mfma, dim3(512), dim3(256), 0, stream,
                       zbuf, w1t, dec_b1, h2bf);

    // decoder GEMM2 (MFMA): h2 -> recon fp32            grid 1024
    hipLaunchKernelGGL(dec2_mfma, dim3(1024), dim3(256), 0, stream,
                       h2bf, w2t, dec_b2, recon_o);
}